// Round 25
// baseline (314.548 us; speedup 1.0000x reference)
//
#include <hip/hip_runtime.h>
#include <stdint.h>

// Binarized dense via i8 MFMA: C[r][u] = dot(sign(x[r,:]), sign(W[:,u])) + b[u]
// sign in {+1,-1} as i8 0x01/0xFF; i32 accumulation exact (|dot| <= 4096).
// v_mfma_i32_32x32x32_i8: A/B = v4i (16 i8), lane&31 = row/col, lane>>5 =
// k-16-half; C/D: col = lane&31, row = (r&3)+8*(r>>2)+4*(lane>>5).
// Layouts/maps HW-verified (rounds 12-24, absmax 0).
//
// v20 = r22 winner + IN-BLOCK SPLIT-K (TLP fix):
// r22 measured ~3000 cyc/step vs ~650 cyc of issued work -> ~2300 cyc of
// dependency stall with only 2 waves/SIMD to hide it. This version keeps the
// EXACT per-wave structure (64x64 tile, on-demand register B, oct-periods,
// non-draining barriers) but runs 16 waves/block (1024 thr):
//   group 0 (waves 0-7)  computes K-steps  0..31,
//   group 1 (waves 8-15) computes K-steps 32..63, concurrently
// -> 4 waves/SIMD, zero extra global traffic (x read once, B once/step).
// Af is per-group: [grp][2 buf][8 sip][4 KB] = 128 KB LDS, 1 block/CU.
// Epilogue: group 1 writes its 64 i32 partials to LDS (lane-fast layout,
// conflict-free), group 0 adds and stores C (+bias). Integer sums: exact.
// __launch_bounds__(1024,1): 128-VGPR cap under both observed 2nd-arg
// semantics (demand ~124). r17's 64-cap failure was (1024,2).

#define BATCH  16384
#define UNITS  512
#define KDIM   4096
#define KSTEP  64
#define NSTEP  64
#define MROWS  64               // rows per block

typedef int v4i  __attribute__((ext_vector_type(4)));
typedef int v16i __attribute__((ext_vector_type(16)));

// split-protocol barrier: lgkm-drain only; vmcnt loads stay in flight
#define BARRIER()                                                              \
    do {                                                                       \
        asm volatile("s_waitcnt lgkmcnt(0)" ::: "memory");                     \
        __builtin_amdgcn_s_barrier();                                          \
        __builtin_amdgcn_sched_barrier(0);                                     \
    } while (0)

// ---- pack W: f32 [4096][512] -> Wb2 fragment-major i8 +/-1 (2 MB) ----------
// 16B chunk index ((s*16 + n5)*2 + ks)*64 + lane; lane = (n&31) + 32*k16half;
// covers col n5*32+(n&31), k = s*64 + ks*32 + k16half*16 + [0..15].
__global__ __launch_bounds__(256) void pack_w_kernel(const float* __restrict__ W,
                                                     uint8_t* __restrict__ Wb2) {
    int t  = blockIdx.x * 256 + threadIdx.x;   // 0..262143
    int n  = t & 511;                          // col
    int k0 = (t >> 9) * 8;                     // 8 consecutive k
    unsigned long long m = 0;
    #pragma unroll
    for (int j = 0; j < 8; ++j) {
        float v = W[(size_t)(k0 + j) * UNITS + n];
        m |= ((v < 0.f) ? 0xFFull : 0x01ull) << (8 * j);
    }
    int s  = k0 >> 6;
    int kk = k0 & 63;
    int ks = kk >> 5;
    int hi = (kk & 31) >> 4;
    int lane = (n & 31) + 32 * hi;
    size_t a = ((((size_t)s * 16 + (n >> 5)) * 2 + ks) * 64 + lane) * 16 + (kk & 15);
    *reinterpret_cast<unsigned long long*>(Wb2 + a) = m;
}

__device__ __forceinline__ uint32_t sgn4(float4 v) {
    uint32_t b0 = v.x < 0.f ? 0xFFu : 0x01u;
    uint32_t b1 = v.y < 0.f ? 0xFFu : 0x01u;
    uint32_t b2 = v.z < 0.f ? 0xFFu : 0x01u;
    uint32_t b3 = v.w < 0.f ? 0xFFu : 0x01u;
    return b0 | (b1 << 8) | (b2 << 16) | (b3 << 24);
}

// Af: byte = afbase + PB*32768 + sip*4096 + rt*2048 + ks*1024
//          + ((row&31) + 32*k16half)*16 + off     (afbase = grp*65536)

// one K-step (group-local step 8Q+SIP): 4 B-frags on demand, 8 MFMA
#define STEP(PB, SIP, Q)                                                       \
    {                                                                          \
        const uint8_t* _b = bbase + (size_t)(sbase + 8 * (Q) + (SIP)) * 32768; \
        v4i b0 = *reinterpret_cast<const v4i*>(_b);            /* ct0 ks0 */   \
        v4i b1 = *reinterpret_cast<const v4i*>(_b + 1024);     /* ct0 ks1 */   \
        v4i b2 = *reinterpret_cast<const v4i*>(_b + 2048);     /* ct1 ks0 */   \
        v4i b3 = *reinterpret_cast<const v4i*>(_b + 3072);     /* ct1 ks1 */   \
        const uint8_t* _a = &Af[afbase + (PB) * 32768 + (SIP) * 4096 + l * 16];\
        v4i a00 = *reinterpret_cast<const v4i*>(_a);           /* rt0 ks0 */   \
        v4i a01 = *reinterpret_cast<const v4i*>(_a + 1024);    /* rt0 ks1 */   \
        v4i a10 = *reinterpret_cast<const v4i*>(_a + 2048);    /* rt1 ks0 */   \
        v4i a11 = *reinterpret_cast<const v4i*>(_a + 3072);    /* rt1 ks1 */   \
        __builtin_amdgcn_s_setprio(1);                                         \
        acc00 = __builtin_amdgcn_mfma_i32_32x32x32_i8(a00, b0, acc00, 0, 0, 0);\
        acc00 = __builtin_amdgcn_mfma_i32_32x32x32_i8(a01, b1, acc00, 0, 0, 0);\
        acc01 = __builtin_amdgcn_mfma_i32_32x32x32_i8(a00, b2, acc01, 0, 0, 0);\
        acc01 = __builtin_amdgcn_mfma_i32_32x32x32_i8(a01, b3, acc01, 0, 0, 0);\
        acc10 = __builtin_amdgcn_mfma_i32_32x32x32_i8(a10, b0, acc10, 0, 0, 0);\
        acc10 = __builtin_amdgcn_mfma_i32_32x32x32_i8(a11, b1, acc10, 0, 0, 0);\
        acc11 = __builtin_amdgcn_mfma_i32_32x32x32_i8(a10, b2, acc11, 0, 0, 0);\
        acc11 = __builtin_amdgcn_mfma_i32_32x32x32_i8(a11, b3, acc11, 0, 0, 0);\
        __builtin_amdgcn_s_setprio(0);                                         \
    }

// load this thread's 2 x-float4s (rows trow, trow+32), group-local step SL
#define XLD2(XA, XB, SL)                                                       \
    {                                                                          \
        const int _sc = sbase + (((SL) < 32) ? (SL) : 31);                     \
        XA = *reinterpret_cast<const float4*>(xr0 + (size_t)_sc * KSTEP);      \
        XB = *reinterpret_cast<const float4*>(xr0 + (size_t)32 * KDIM          \
                                                  + (size_t)_sc * KSTEP);      \
    }

// commit the pair into Af[grp][PB], step-slot SIP (rt 0 and 1)
#define XCM2(PB, SIP, XA, XB)                                                  \
    {                                                                          \
        *reinterpret_cast<uint32_t*>(                                          \
            &Af[afbase + (PB) * 32768 + (SIP) * 4096 + awk]) = sgn4(XA);       \
        *reinterpret_cast<uint32_t*>(                                          \
            &Af[afbase + (PB) * 32768 + (SIP) * 4096 + 2048 + awk]) = sgn4(XB);\
    }

// one oct-period (group-local steps 8Q..8Q+7 from Af[PB]; commits next 8)
#define PERIOD(Q, PB)                                                          \
    {                                                                          \
        STEP(PB, 0, Q);                                                        \
        XLD2(xB0, xB1, 8 * (Q) + 9);                                           \
        STEP(PB, 1, Q);                                                        \
        XCM2((PB) ^ 1, 0, xA0, xA1);                                           \
        XLD2(xA0, xA1, 8 * (Q) + 10);                                          \
        STEP(PB, 2, Q);                                                        \
        XCM2((PB) ^ 1, 1, xB0, xB1);                                           \
        XLD2(xB0, xB1, 8 * (Q) + 11);                                          \
        STEP(PB, 3, Q);                                                        \
        XCM2((PB) ^ 1, 2, xA0, xA1);                                           \
        XLD2(xA0, xA1, 8 * (Q) + 12);                                          \
        STEP(PB, 4, Q);                                                        \
        XCM2((PB) ^ 1, 3, xB0, xB1);                                           \
        XLD2(xB0, xB1, 8 * (Q) + 13);                                          \
        STEP(PB, 5, Q);                                                        \
        XCM2((PB) ^ 1, 4, xA0, xA1);                                           \
        XLD2(xA0, xA1, 8 * (Q) + 14);                                          \
        STEP(PB, 6, Q);                                                        \
        XCM2((PB) ^ 1, 5, xB0, xB1);                                           \
        XLD2(xB0, xB1, 8 * (Q) + 15);                                          \
        STEP(PB, 7, Q);                                                        \
        XCM2((PB) ^ 1, 6, xA0, xA1);                                           \
        XLD2(xA0, xA1, 8 * (Q) + 16);                                          \
        XCM2((PB) ^ 1, 7, xB0, xB1);                                           \
        BARRIER();                                                             \
    }

// ------------------------------- MFMA GEMM ----------------------------------
__global__ __launch_bounds__(1024, 1) void mm_kernel(const float* __restrict__ x,
                                                     const uint8_t* __restrict__ Wb2,
                                                     const float* __restrict__ bias,
                                                     float* __restrict__ C) {
    __shared__ __attribute__((aligned(16))) uint8_t Af[131072];  // 128 KB
    const int t   = threadIdx.x;
    const int l   = t & 63;
    const int wv  = t >> 6;              // wave 0..15
    const int grp = wv >> 3;             // K-half group 0/1
    const int wvg = wv & 7;              // within-group wave -> cols wvg*64..+63
    const int lr  = l & 31;
    const int hi  = l >> 5;
    const int row0  = blockIdx.x * MROWS;
    const int sbase = grp * 32;          // group's first K-step
    const int afbase = grp * 65536;

    // x staging (within group, 512 threads): thread owns rows trow & trow+32
    const int tg   = t & 511;
    const int trow = tg >> 4;            // 0..31
    const int tak  = (tg & 15) * 4;      // 0..60
    const int awk = (tak >> 5) * 1024
                  + (trow + 32 * ((tak >> 4) & 1)) * 16 + (tak & 15);
    const float* xr0 = x + (size_t)(row0 + trow) * KDIM + tak;
    // B base (verified): n5 = wvg*2 + ct; ct stride 2048, ks stride 1024
    const uint8_t* bbase = Wb2 + ((size_t)(wvg * 2) * 2 * 64 + l) * 16;

    v16i acc00, acc01, acc10, acc11;
    #pragma unroll
    for (int e = 0; e < 16; ++e) { acc00[e] = 0; acc01[e] = 0;
                                   acc10[e] = 0; acc11[e] = 0; }

    float4 xA0, xA1, xB0, xB1;

    // ---- prologue: stage group-local steps 0..7 into Af[grp][0] ----
    {
        float4 xa, xb;
        XLD2(xa, xb, 0); XCM2(0, 0, xa, xb);
        XLD2(xa, xb, 1); XCM2(0, 1, xa, xb);
        XLD2(xa, xb, 2); XCM2(0, 2, xa, xb);
        XLD2(xa, xb, 3); XCM2(0, 3, xa, xb);
        XLD2(xa, xb, 4); XCM2(0, 4, xa, xb);
        XLD2(xa, xb, 5); XCM2(0, 5, xa, xb);
        XLD2(xa, xb, 6); XCM2(0, 6, xa, xb);
        XLD2(xa, xb, 7); XCM2(0, 7, xa, xb);
        XLD2(xA0, xA1, 8);
        BARRIER();
    }

    // 4 oct-periods per group (32 K-steps each)
    PERIOD(0, 0);
    PERIOD(1, 1);
    PERIOD(2, 0);
    PERIOD(3, 1);

    // ---- cross-group reduction + epilogue ----
    __syncthreads();                      // full drain; Af reusable
    int* red = reinterpret_cast<int*>(Af);
    const int rbase = wvg * 4096 + l;     // lane-fast: conflict-free
    if (grp == 1) {
        #pragma unroll
        for (int r = 0; r < 16; ++r) {
            red[rbase + (r)      * 64] = acc00[r];
            red[rbase + (16 + r) * 64] = acc01[r];
            red[rbase + (32 + r) * 64] = acc10[r];
            red[rbase + (48 + r) * 64] = acc11[r];
        }
    }
    __syncthreads();
    if (grp == 0) {
        const int col0 = wvg * 64 + lr;          // ct = 0
        const int col1 = wvg * 64 + 32 + lr;     // ct = 1
        const float bv0 = bias[col0], bv1 = bias[col1];
        #pragma unroll
        for (int r = 0; r < 16; ++r) {
            int crow = (r & 3) + 8 * (r >> 2) + 4 * hi;
            int s00 = acc00[r] + red[rbase + (r)      * 64];
            int s01 = acc01[r] + red[rbase + (16 + r) * 64];
            int s10 = acc10[r] + red[rbase + (32 + r) * 64];
            int s11 = acc11[r] + red[rbase + (48 + r) * 64];
            C[(size_t)(row0 + crow) * UNITS + col0]      = (float)s00 + bv0;
            C[(size_t)(row0 + crow) * UNITS + col1]      = (float)s01 + bv1;
            C[(size_t)(row0 + 32 + crow) * UNITS + col0] = (float)s10 + bv0;
            C[(size_t)(row0 + 32 + crow) * UNITS + col1] = (float)s11 + bv1;
        }
    }
}

extern "C" void kernel_launch(void* const* d_in, const int* in_sizes, int n_in,
                              void* d_out, int out_size, void* d_ws, size_t ws_size,
                              hipStream_t stream) {
    const float* x = (const float*)d_in[0];
    const float* W = (const float*)d_in[1];
    const float* b = (const float*)d_in[2];
    float* out = (float*)d_out;

    uint8_t* Wb2 = (uint8_t*)d_ws;   // 2 MB fragment-major packed W

    pack_w_kernel<<<(512 * 512) / 256, 256, 0, stream>>>(W, Wb2);
    mm_kernel<<<BATCH / MROWS, 1024, 0, stream>>>(x, Wb2, b, out);
}

// Round 26
// 90.716 us; speedup vs baseline: 3.4674x; 3.4674x over previous
//
#include <hip/hip_runtime.h>
#include <stdint.h>

// Binarized dense via i8 MFMA: C[r][u] = dot(sign(x[r,:]), sign(W[:,u])) + b[u]
// sign in {+1,-1} as i8 0x01/0xFF; i32 accumulation exact (|dot| <= 4096).
// v_mfma_i32_32x32x32_i8: A/B = v4i (16 i8), lane&31 = row/col, lane>>5 =
// k-16-half; C/D: col = lane&31, row = (r&3)+8*(r>>2)+4*(lane>>5).
// Layouts/maps HW-verified (rounds 12-25, absmax 0).
//
// FINAL (= r22, best measured 89.35us; reproduced 90.9us r24): oct-period
// schedule with non-draining barriers.
//  - block = 64 rows x 512 cols (512 thr, 8 waves), wave = 64x64 output
//    (2x2 32-tiles, acc 64 VGPR); grid 256 = 1 block/CU.
//  - x read from HBM exactly once; sgn4-packed to LDS A-frag dbuf
//    (Af 2x32KB, oct-period: 8 K-steps per barrier -> only 8 barriers).
//  - B on demand from L2 (fragment-major Wb2, 2MB resident; coalesced
//    1KB wave loads straight to registers; no B LDS).
//  - BARRIER() = lgkmcnt(0) + raw s_barrier + sched_barrier(0): vmcnt
//    loads deliberately stay in flight across barriers (T3/T4-lite).
//  - s_setprio(1) around MFMA clusters (T5).
// Search summary (r12-r25): occupancy (8/16/32 waves/CU), wave geometry
// (32x32..64x64), B path (reg/LDS/glds+vmcnt), barrier semantics/density,
// issue order, split-K -- all land 93-558us. Allocator law: 256-thr and
// 1024-thr blocks cap at 64 VGPR; 512-thr at 128. This schedule is the
// measured optimum at HIP source level.

#define BATCH  16384
#define UNITS  512
#define KDIM   4096
#define KSTEP  64
#define NSTEP  (KDIM / KSTEP)   // 64
#define NPER8  (NSTEP / 8)      // 8 oct-periods
#define MROWS  64               // rows per block

typedef int v4i  __attribute__((ext_vector_type(4)));
typedef int v16i __attribute__((ext_vector_type(16)));

// split-protocol barrier: lgkm-drain only; vmcnt loads stay in flight
#define BARRIER()                                                              \
    do {                                                                       \
        asm volatile("s_waitcnt lgkmcnt(0)" ::: "memory");                     \
        __builtin_amdgcn_s_barrier();                                          \
        __builtin_amdgcn_sched_barrier(0);                                     \
    } while (0)

// ---- pack W: f32 [4096][512] -> Wb2 fragment-major i8 +/-1 (2 MB) ----------
// 16B chunk index ((s*16 + n5)*2 + ks)*64 + lane; lane = (n&31) + 32*k16half;
// covers col n5*32+(n&31), k = s*64 + ks*32 + k16half*16 + [0..15].
__global__ __launch_bounds__(256) void pack_w_kernel(const float* __restrict__ W,
                                                     uint8_t* __restrict__ Wb2) {
    int t  = blockIdx.x * 256 + threadIdx.x;   // 0..262143
    int n  = t & 511;                          // col
    int k0 = (t >> 9) * 8;                     // 8 consecutive k
    unsigned long long m = 0;
    #pragma unroll
    for (int j = 0; j < 8; ++j) {
        float v = W[(size_t)(k0 + j) * UNITS + n];
        m |= ((v < 0.f) ? 0xFFull : 0x01ull) << (8 * j);
    }
    int s  = k0 >> 6;
    int kk = k0 & 63;
    int ks = kk >> 5;
    int hi = (kk & 31) >> 4;
    int lane = (n & 31) + 32 * hi;
    size_t a = ((((size_t)s * 16 + (n >> 5)) * 2 + ks) * 64 + lane) * 16 + (kk & 15);
    *reinterpret_cast<unsigned long long*>(Wb2 + a) = m;
}

__device__ __forceinline__ uint32_t sgn4(float4 v) {
    uint32_t b0 = v.x < 0.f ? 0xFFu : 0x01u;
    uint32_t b1 = v.y < 0.f ? 0xFFu : 0x01u;
    uint32_t b2 = v.z < 0.f ? 0xFFu : 0x01u;
    uint32_t b3 = v.w < 0.f ? 0xFFu : 0x01u;
    return b0 | (b1 << 8) | (b2 << 16) | (b3 << 24);
}

// Af layout: byte = PB*32768 + sip*4096 + rt*2048 + ks*1024
//                 + ((row&31) + 32*k16half)*16 + off   (sip = 0..7)

// one K-step: 4 B-frags on demand (L2), 4 A-frags (2rt x 2ks), 8 MFMA
#define STEP(PB, SIP, Q)                                                       \
    {                                                                          \
        const uint8_t* _b = bbase + (size_t)(8 * (Q) + (SIP)) * 32768;         \
        v4i b0 = *reinterpret_cast<const v4i*>(_b);            /* ct0 ks0 */   \
        v4i b1 = *reinterpret_cast<const v4i*>(_b + 1024);     /* ct0 ks1 */   \
        v4i b2 = *reinterpret_cast<const v4i*>(_b + 2048);     /* ct1 ks0 */   \
        v4i b3 = *reinterpret_cast<const v4i*>(_b + 3072);     /* ct1 ks1 */   \
        const uint8_t* _a = &Af[(PB) * 32768 + (SIP) * 4096 + l * 16];         \
        v4i a00 = *reinterpret_cast<const v4i*>(_a);           /* rt0 ks0 */   \
        v4i a01 = *reinterpret_cast<const v4i*>(_a + 1024);    /* rt0 ks1 */   \
        v4i a10 = *reinterpret_cast<const v4i*>(_a + 2048);    /* rt1 ks0 */   \
        v4i a11 = *reinterpret_cast<const v4i*>(_a + 3072);    /* rt1 ks1 */   \
        __builtin_amdgcn_s_setprio(1);                                         \
        acc00 = __builtin_amdgcn_mfma_i32_32x32x32_i8(a00, b0, acc00, 0, 0, 0);\
        acc00 = __builtin_amdgcn_mfma_i32_32x32x32_i8(a01, b1, acc00, 0, 0, 0);\
        acc01 = __builtin_amdgcn_mfma_i32_32x32x32_i8(a00, b2, acc01, 0, 0, 0);\
        acc01 = __builtin_amdgcn_mfma_i32_32x32x32_i8(a01, b3, acc01, 0, 0, 0);\
        acc10 = __builtin_amdgcn_mfma_i32_32x32x32_i8(a10, b0, acc10, 0, 0, 0);\
        acc10 = __builtin_amdgcn_mfma_i32_32x32x32_i8(a11, b1, acc10, 0, 0, 0);\
        acc11 = __builtin_amdgcn_mfma_i32_32x32x32_i8(a10, b2, acc11, 0, 0, 0);\
        acc11 = __builtin_amdgcn_mfma_i32_32x32x32_i8(a11, b3, acc11, 0, 0, 0);\
        __builtin_amdgcn_s_setprio(0);                                         \
    }

// load this thread's 2 x-float4s (rows trow, trow+32) of absolute step S
#define XLD2(XA, XB, S)                                                        \
    {                                                                          \
        const int _sc = ((S) < NSTEP) ? (S) : NSTEP - 1;                       \
        XA = *reinterpret_cast<const float4*>(xr0 + (size_t)_sc * KSTEP);      \
        XB = *reinterpret_cast<const float4*>(xr0 + (size_t)32 * KDIM          \
                                                  + (size_t)_sc * KSTEP);      \
    }

// commit the pair into Af[PB], step-slot SIP (rt 0 and 1)
#define XCM2(PB, SIP, XA, XB)                                                  \
    {                                                                          \
        *reinterpret_cast<uint32_t*>(                                          \
            &Af[(PB) * 32768 + (SIP) * 4096 + awk]) = sgn4(XA);                \
        *reinterpret_cast<uint32_t*>(                                          \
            &Af[(PB) * 32768 + (SIP) * 4096 + 2048 + awk]) = sgn4(XB);         \
    }

// one oct-period: steps 8Q..8Q+7 read Af[PB]; commits A(8Q+8..+15) -> Af[PB^1]
// steady state: entering PERIOD(Q), (xA0,xA1) holds step 8Q+8 data.
#define PERIOD(Q, PB)                                                          \
    {                                                                          \
        STEP(PB, 0, Q);                                                        \
        XLD2(xB0, xB1, 8 * (Q) + 9);                                           \
        STEP(PB, 1, Q);                                                        \
        XCM2((PB) ^ 1, 0, xA0, xA1);                                           \
        XLD2(xA0, xA1, 8 * (Q) + 10);                                          \
        STEP(PB, 2, Q);                                                        \
        XCM2((PB) ^ 1, 1, xB0, xB1);                                           \
        XLD2(xB0, xB1, 8 * (Q) + 11);                                          \
        STEP(PB, 3, Q);                                                        \
        XCM2((PB) ^ 1, 2, xA0, xA1);                                           \
        XLD2(xA0, xA1, 8 * (Q) + 12);                                          \
        STEP(PB, 4, Q);                                                        \
        XCM2((PB) ^ 1, 3, xB0, xB1);                                           \
        XLD2(xB0, xB1, 8 * (Q) + 13);                                          \
        STEP(PB, 5, Q);                                                        \
        XCM2((PB) ^ 1, 4, xA0, xA1);                                           \
        XLD2(xA0, xA1, 8 * (Q) + 14);                                          \
        STEP(PB, 6, Q);                                                        \
        XCM2((PB) ^ 1, 5, xB0, xB1);                                           \
        XLD2(xB0, xB1, 8 * (Q) + 15);                                          \
        STEP(PB, 7, Q);                                                        \
        XCM2((PB) ^ 1, 6, xA0, xA1);                                           \
        XLD2(xA0, xA1, 8 * (Q) + 16);  /* = 8(Q+1)+8: next period's sip0 */    \
        XCM2((PB) ^ 1, 7, xB0, xB1);                                           \
        BARRIER();                                                             \
    }

// ------------------------------- MFMA GEMM ----------------------------------
__global__ __launch_bounds__(512, 1) void mm_kernel(const float* __restrict__ x,
                                                    const uint8_t* __restrict__ Wb2,
                                                    const float* __restrict__ bias,
                                                    float* __restrict__ C) {
    __shared__ __attribute__((aligned(16))) uint8_t Af[2 * 32768];  // 64 KB
    const int t   = threadIdx.x;
    const int l   = t & 63;
    const int wv  = t >> 6;              // wave 0..7 -> cols wv*64..+63
    const int lr  = l & 31;
    const int hi  = l >> 5;
    const int row0 = blockIdx.x * MROWS;

    // x staging (verified): thread t owns rows trow & trow+32, f4 at tak
    const int trow = t >> 4;             // 0..31
    const int tak  = (t & 15) * 4;       // 0..60
    const int awk = (tak >> 5) * 1024
                  + (trow + 32 * ((tak >> 4) & 1)) * 16 + (tak & 15);
    const float* xr0 = x + (size_t)(row0 + trow) * KDIM + tak;
    // B base (verified): n5 = wv*2 + ct; ct stride 2048, ks stride 1024
    const uint8_t* bbase = Wb2 + ((size_t)(wv * 2) * 2 * 64 + l) * 16;

    v16i acc00, acc01, acc10, acc11;
    #pragma unroll
    for (int e = 0; e < 16; ++e) { acc00[e] = 0; acc01[e] = 0;
                                   acc10[e] = 0; acc11[e] = 0; }

    float4 xA0, xA1, xB0, xB1;

    // ---- prologue: stage steps 0..7 into Af[0]; preload xA = step 8 ----
    {
        float4 xa, xb;
        XLD2(xa, xb, 0); XCM2(0, 0, xa, xb);
        XLD2(xa, xb, 1); XCM2(0, 1, xa, xb);
        XLD2(xa, xb, 2); XCM2(0, 2, xa, xb);
        XLD2(xa, xb, 3); XCM2(0, 3, xa, xb);
        XLD2(xa, xb, 4); XCM2(0, 4, xa, xb);
        XLD2(xa, xb, 5); XCM2(0, 5, xa, xb);
        XLD2(xa, xb, 6); XCM2(0, 6, xa, xb);
        XLD2(xa, xb, 7); XCM2(0, 7, xa, xb);
        XLD2(xA0, xA1, 8);
        BARRIER();
    }

    #pragma unroll 1
    for (int q = 0; q < NPER8; q += 2) {
        PERIOD(q,     0);
        PERIOD(q + 1, 1);
    }

    // ---- epilogue: C = acc + bias (verified C/D map) ----
    {
        const int col0 = wv * 64 + lr;          // ct = 0
        const int col1 = wv * 64 + 32 + lr;     // ct = 1
        const float bv0 = bias[col0], bv1 = bias[col1];
        #pragma unroll
        for (int r = 0; r < 16; ++r) {
            int crow = (r & 3) + 8 * (r >> 2) + 4 * hi;
            C[(size_t)(row0 + crow) * UNITS + col0]      = (float)acc00[r] + bv0;
            C[(size_t)(row0 + crow) * UNITS + col1]      = (float)acc01[r] + bv1;
            C[(size_t)(row0 + 32 + crow) * UNITS + col0] = (float)acc10[r] + bv0;
            C[(size_t)(row0 + 32 + crow) * UNITS + col1] = (float)acc11[r] + bv1;
        }
    }
}

extern "C" void kernel_launch(void* const* d_in, const int* in_sizes, int n_in,
                              void* d_out, int out_size, void* d_ws, size_t ws_size,
                              hipStream_t stream) {
    const float* x = (const float*)d_in[0];
    const float* W = (const float*)d_in[1];
    const float* b = (const float*)d_in[2];
    float* out = (float*)d_out;

    uint8_t* Wb2 = (uint8_t*)d_ws;   // 2 MB fragment-major packed W

    pack_w_kernel<<<(512 * 512) / 256, 256, 0, stream>>>(W, Wb2);
    mm_kernel<<<BATCH / MROWS, 512, 0, stream>>>(x, Wb2, b, out);
}